// Round 7
// baseline (900.958 us; speedup 1.0000x reference)
//
#include <hip/hip_runtime.h>
#include <math.h>

// Soft-Viterbi structured decoding: B=32, T=512, N=128, fp32.
// Round-7: ONE WAVE PER BATCH ELEMENT — fully barrier-free.
// 32 blocks x 64 threads. The whole normalized transition matrix lives in
// the wave's registers (256 VGPRs; 1 wave/SIMD so budget is 512).
// Same-wave LDS ops are processed in order by the DS pipe, so the per-step
// alpha exchange (ds_write -> ds_read of ubuf) needs NO s_barrier and NO
// explicit lgkmcnt: hardware guarantees RAW through LDS within a wave;
// compiler reordering is suppressed with zero-cost asm memory fences.
// This removes the two dominant per-step costs of the 4-wave version:
// the barrier (~100-150cy) and 4-wave DS-pipe serialization (~100cy),
// plus the r0 LDS broadcast (alpha[0] now comes from readfirstlane).
//
// Layout: quad g = lane>>2 owns states [8g,8g+8); lane k = lane&3 sums
// K-granules k+4i (i=0..7) -> 8 ds_read_b128, 16-way broadcast, no
// conflicts. Dot = 8 states x 16 pk-FMA; combine = quad DPP (xor1,xor2);
// lane keeps states s0=8g+2k, s0+1 via cndmask select.

#define TT 512
#define BB 32
#define NN 128
#define EPSC 1e-10f
#define TINY 1e-33f

typedef float v2f __attribute__((ext_vector_type(2)));

// Zero-cost compiler memory fence: stops LLVM hoisting this step's LDS
// reads above the previous LDS write (HW DS pipe is in-order per wave).
#define CFENCE() asm volatile("" ::: "memory")

__device__ __forceinline__ float rcp_fast(float x) {
  return __builtin_amdgcn_rcpf(x);
}
__device__ __forceinline__ float qswap1(float x) {
  return __int_as_float(__builtin_amdgcn_mov_dpp(__float_as_int(x), 0xB1, 0xF, 0xF, true));
}
__device__ __forceinline__ float qswap2(float x) {
  return __int_as_float(__builtin_amdgcn_mov_dpp(__float_as_int(x), 0x4E, 0xF, 0xF, true));
}

// 32-element partial dot: 16 packed FMAs, 2 independent chains.
__device__ __forceinline__ float dot16pk(const v2f* av, const v2f* tm) {
  v2f a0 = av[0] * tm[0];
  v2f a1 = av[1] * tm[1];
  #pragma unroll
  for (int j = 2; j < 16; j += 2) {
    a0 = __builtin_elementwise_fma(av[j+0], tm[j+0], a0);
    a1 = __builtin_elementwise_fma(av[j+1], tm[j+1], a1);
  }
  v2f s = a0 + a1;
  return s.x + s.y;
}

__global__ __launch_bounds__(64, 1)
void soft_viterbi_kernel(const float* __restrict__ trans,
                         const float* __restrict__ emis,
                         const float* __restrict__ prior,
                         float* __restrict__ out) {
  const int b    = blockIdx.x;
  const int lane = threadIdx.x;          // 0..63, one wave
  const int g    = lane >> 2;            // quad id: 8 states
  const int k    = lane & 3;             // K-chunk within quad
  const int s0   = 8 * g + 2 * k;        // this lane's 2 output states
  const int nf0  = 8 * g;                // fragment state base
  const bool k1  = (k & 1) != 0;
  const bool k2  = (k & 2) != 0;

  __shared__ __align__(16) float ubuf[NN];   // single alpha~/q exchange buffer
  __shared__ __align__(16) float sarr[TT];   // sarr[t] = 1/alpha~_t[0]
  __shared__ __align__(16) float red[NN];    // transition row sums

  const float* emB = emis + (size_t)b * TT * NN;
  float* outb      = out  + (size_t)b * TT * NN;

  // ---- early global loads ----
  float2 pr2 = *(const float2*)(prior + s0);
  float2 em0 = *(const float2*)(emB + s0);
  float2 e1  = *(const float2*)(emB + 1 * NN + s0);
  float2 e2  = *(const float2*)(emB + 2 * NN + s0);
  float2 e3  = *(const float2*)(emB + 3 * NN + s0);
  pr2.x = fmaxf(pr2.x, EPSC); pr2.y = fmaxf(pr2.y, EPSC);

  // ---- row sums of clipped transition: 2 rows per lane ----
  #pragma unroll
  for (int rr = 0; rr < 2; ++rr) {
    const int r = 2 * lane + rr;
    const float4* row = (const float4*)(trans + r * NN);
    float s = 0.f;
    #pragma unroll 8
    for (int j = 0; j < NN / 4; ++j) {
      float4 v = row[j];
      s += fmaxf(v.x, EPSC) + fmaxf(v.y, EPSC) + fmaxf(v.z, EPSC) + fmaxf(v.w, EPSC);
    }
    red[r] = s;
  }
  CFENCE();   // in-order DS pipe makes red[] reads below see the writes

  // ---- forward fragments: tf[s][2i+(c>>1)][c&1] = Tn[p][nf0+s], p=4(k+4i)+c ----
  v2f tf[8][16];
  #pragma unroll
  for (int i = 0; i < 8; ++i) {
    #pragma unroll
    for (int c = 0; c < 4; ++c) {
      const int p = 4 * (k + 4 * i) + c;
      const float4 ta = *(const float4*)(trans + p * NN + nf0);
      const float4 tc = *(const float4*)(trans + p * NN + nf0 + 4);
      const float ir = 1.0f / red[p];
      const int jj = 2 * i + (c >> 1); const int ee = c & 1;
      tf[0][jj][ee] = fmaxf(ta.x, EPSC) * ir;
      tf[1][jj][ee] = fmaxf(ta.y, EPSC) * ir;
      tf[2][jj][ee] = fmaxf(ta.z, EPSC) * ir;
      tf[3][jj][ee] = fmaxf(ta.w, EPSC) * ir;
      tf[4][jj][ee] = fmaxf(tc.x, EPSC) * ir;
      tf[5][jj][ee] = fmaxf(tc.y, EPSC) * ir;
      tf[6][jj][ee] = fmaxf(tc.z, EPSC) * ir;
      tf[7][jj][ee] = fmaxf(tc.w, EPSC) * ir;
    }
  }

  // ---- prior normalization (one-time, shfl fine) ----
  float vv = pr2.x + pr2.y;
  #pragma unroll
  for (int m = 1; m < 64; m <<= 1) vv += __shfl_xor(vv, m, 64);
  const float psum = vv;

  // ---- u0 = alpha~_0 ----
  float an0 = (pr2.x / psum) * __expf(em0.x);
  float an1 = (pr2.y / psum) * __expf(em0.y);
  *(float2*)&ubuf[s0] = make_float2(an0, an1);
  *(float2*)(outb + s0) = make_float2(an0, an1);
  float rinv = rcp_fast(__int_as_float(__builtin_amdgcn_readfirstlane(__float_as_int(an0))));
  if (lane == 0) sarr[0] = rinv;        // 1/alpha~_0[0]
  float dc0 = __expf(e1.x), dc1 = __expf(e1.y);  // d_1
  float2 eh1 = e2;                      // em[t+1] invariant
  float2 eh2 = e3;                      // em[t+2] invariant

  // ================= forward (barrier-free) =================
  // Entering step t: dc = d_t, rinv = 1/alpha~_{t-1}[0], ubuf = alpha~_{t-1}.
  for (int t = 1; t < TT; ++t) {
    CFENCE();                            // order prior ubuf write vs these reads
    float4 a4[8];
    #pragma unroll
    for (int i = 0; i < 8; ++i) a4[i] = *(const float4*)&ubuf[4 * (k + 4 * i)];
    // off-chain work under LDS latency:
    const float ndc0 = __expf(eh1.x), ndc1 = __expf(eh1.y);  // d_{t+1}
    eh1 = eh2;
    const int tpre = (t + 3 < TT) ? (t + 3) : (TT - 1);
    eh2 = *(const float2*)(emB + (size_t)tpre * NN + s0);
    const v2f* av = (const v2f*)a4;
    float z[8];
    #pragma unroll
    for (int s = 0; s < 8; ++s) z[s] = dot16pk(av, tf[s]);
    #pragma unroll
    for (int s = 0; s < 8; ++s) { z[s] += qswap1(z[s]); z[s] += qswap2(z[s]); }
    const float zl0 = k1 ? z[2] : z[0], zl1 = k1 ? z[3] : z[1];
    const float zh0 = k1 ? z[6] : z[4], zh1 = k1 ? z[7] : z[5];
    const float za = k2 ? zh0 : zl0;     // full sum, state s0
    const float zb = k2 ? zh1 : zl1;     // full sum, state s0+1
    an0 = (dc0 * rinv) * za;
    an1 = (dc1 * rinv) * zb;
    *(float2*)&ubuf[s0] = make_float2(an0, an1);
    if (t < TT - 1) *(float2*)(outb + (size_t)t * NN + s0) = make_float2(an0, an1);
    rinv = rcp_fast(__int_as_float(__builtin_amdgcn_readfirstlane(__float_as_int(an0))));
    if (lane == 0) sarr[t] = rinv;       // 1/alpha~_t[0]
    dc0 = ndc0; dc1 = ndc1;
  }
  const float dl0 = dc0, dl1 = dc1;      // = d_{T-1} (clamped ring)

  // ================= final softmax =================
  float v2 = an0 + an1;
  #pragma unroll
  for (int m = 1; m < 64; m <<= 1) v2 += __shfl_xor(v2, m, 64);
  const float itot = 1.0f / v2;
  float pc0 = an0 * itot, pc1 = an1 * itot;
  *(float2*)(outb + (size_t)(TT - 1) * NN + s0) = make_float2(pc0, pc1);

  // Drain: forward alpha-stash stores must be visible before re-reads.
  asm volatile("s_waitcnt vmcnt(0)" ::: "memory");

  // ---- backward fragments: tb[s][2i+(c>>1)][c&1] = Tn[nf0+s][4(k+4i)+c] ----
  // (tf is dead now; register allocator reuses its 256 VGPRs.)
  v2f tb[8][16];
  #pragma unroll
  for (int s = 0; s < 8; ++s) {
    const float ir = 1.0f / red[nf0 + s];
    const float4* rr = (const float4*)(trans + (nf0 + s) * NN);
    #pragma unroll
    for (int i = 0; i < 8; ++i) {
      const float4 tv = rr[k + 4 * i];
      tb[s][2*i+0][0] = fmaxf(tv.x, EPSC) * ir;
      tb[s][2*i+0][1] = fmaxf(tv.y, EPSC) * ir;
      tb[s][2*i+1][0] = fmaxf(tv.z, EPSC) * ir;
      tb[s][2*i+1][1] = fmaxf(tv.w, EPSC) * ir;
    }
  }

  // ---- backward init ----
  float2 ec_cur = *(const float2*)(outb + (size_t)(TT - 2) * NN + s0);  // alpha~_{T-2}
  float2 ec_h   = *(const float2*)(outb + (size_t)(TT - 3) * NN + s0);  // alpha~_{T-3}
  float2 em_b1  = *(const float2*)(emB  + (size_t)(TT - 2) * NN + s0);  // em[T-2]
  float2 em_b2  = *(const float2*)(emB  + (size_t)(TT - 3) * NN + s0);  // em[T-3]
  const float sl = sarr[TT - 2];
  float g0 = dl0 * sl * rcp_fast(fmaxf(an0, TINY));   // g_{T-2}
  float g1 = dl1 * sl * rcp_fast(fmaxf(an1, TINY));

  // ================= backward (barrier-free) =================
  // Entering step t: pc = p_{t+1}, g = g_t, ec_cur = alpha~_t,
  // em_b1 = em[t], em_b2 = em[t-1].
  for (int t = TT - 2; t >= 0; --t) {
    CFENCE();
    *(float2*)&ubuf[s0] = make_float2(pc0 * g0, pc1 * g1);   // q_t
    CFENCE();                            // reads below must follow the write
    float4 a4[8];
    #pragma unroll
    for (int i = 0; i < 8; ++i) a4[i] = *(const float4*)&ubuf[4 * (k + 4 * i)];
    // off-chain prep for iter t-1:
    const float sr = sarr[(t > 0) ? (t - 1) : 0];
    const float at0 = ec_cur.x, at1 = ec_cur.y;              // alpha~_t
    const float gn0 = __expf(em_b1.x) * sr * rcp_fast(fmaxf(at0, TINY));
    const float gn1 = __expf(em_b1.y) * sr * rcp_fast(fmaxf(at1, TINY));
    em_b1 = em_b2;
    const int tp = (t >= 2) ? (t - 2) : 0;
    em_b2 = *(const float2*)(emB + (size_t)tp * NN + s0);
    const v2f* av = (const v2f*)a4;
    float z[8];
    #pragma unroll
    for (int s = 0; s < 8; ++s) z[s] = dot16pk(av, tb[s]);
    #pragma unroll
    for (int s = 0; s < 8; ++s) { z[s] += qswap1(z[s]); z[s] += qswap2(z[s]); }
    const float zl0 = k1 ? z[2] : z[0], zl1 = k1 ? z[3] : z[1];
    const float zh0 = k1 ? z[6] : z[4], zh1 = k1 ? z[7] : z[5];
    const float za = k2 ? zh0 : zl0;
    const float zb = k2 ? zh1 : zl1;
    pc0 = at0 * za;                                          // p_t
    pc1 = at1 * zb;
    *(float2*)(outb + (size_t)t * NN + s0) = make_float2(pc0, pc1);
    g0 = gn0; g1 = gn1;
    ec_cur = ec_h;                                           // alpha~_{t-1}
    ec_h = *(const float2*)(outb + (size_t)tp * NN + s0);    // alpha~_{t-2}
  }
}

extern "C" void kernel_launch(void* const* d_in, const int* in_sizes, int n_in,
                              void* d_out, int out_size, void* d_ws, size_t ws_size,
                              hipStream_t stream) {
  (void)in_sizes; (void)n_in; (void)d_ws; (void)ws_size; (void)out_size;
  const float* trans = (const float*)d_in[0];
  const float* emis  = (const float*)d_in[1];
  const float* prior = (const float*)d_in[2];
  float* out = (float*)d_out;
  soft_viterbi_kernel<<<dim3(BB), dim3(64), 0, stream>>>(trans, emis, prior, out);
}

// Round 8
// 505.334 us; speedup vs baseline: 1.7829x; 1.7829x over previous
//
#include <hip/hip_runtime.h>
#include <math.h>

// Soft-Viterbi structured decoding: B=32, T=512, N=128, fp32.
// Round-8: TWO batch elements per block (16 blocks x 512 threads).
// Round-7 proved 1 wave/element is issue-bound (4x per-wave FMA issue,
// 900us); round-6's 4-wave split is latency-bound (~280cy/step of LDS
// round-trip + barrier dead time because each SIMD hosts ONE wave).
// Fix: co-schedule two independent 4-wave groups (one per batch element)
// in one workgroup -> 2 waves/SIMD. While group A stalls on ds_read
// latency/barrier arrival, group B's wave on the same SIMD issues FMAs.
// One shared s_barrier per step syncs both groups (same cadence).
// Per-wave step code is identical to round 6 (pk-FMA dot, DPP quad
// combine, rcp scale factors, depth-4 em rings, LDS-only barrier).

#define TT 512
#define BB 32
#define NN 128
#define EPSC 1e-10f
#define TINY 1e-33f

typedef float v2f __attribute__((ext_vector_type(2)));

// Fused LDS-drain + barrier. No vmcnt wait (global ops stay in flight).
#define BAR() asm volatile("s_waitcnt lgkmcnt(0)\n\ts_barrier" ::: "memory")

__device__ __forceinline__ float rcp_fast(float x) {
  return __builtin_amdgcn_rcpf(x);
}
__device__ __forceinline__ float qswap1(float x) {
  return __int_as_float(__builtin_amdgcn_mov_dpp(__float_as_int(x), 0xB1, 0xF, 0xF, true));
}
__device__ __forceinline__ float qswap2(float x) {
  return __int_as_float(__builtin_amdgcn_mov_dpp(__float_as_int(x), 0x4E, 0xF, 0xF, true));
}

// 32-element partial dot via 16 packed FMAs (4 independent chains).
__device__ __forceinline__ float dotpk16(const v2f* av, const v2f tm[16]) {
  v2f a0 = av[0] * tm[0];
  v2f a1 = av[1] * tm[1];
  v2f a2 = av[2] * tm[2];
  v2f a3 = av[3] * tm[3];
  #pragma unroll
  for (int j = 4; j < 16; j += 4) {
    a0 = __builtin_elementwise_fma(av[j+0], tm[j+0], a0);
    a1 = __builtin_elementwise_fma(av[j+1], tm[j+1], a1);
    a2 = __builtin_elementwise_fma(av[j+2], tm[j+2], a2);
    a3 = __builtin_elementwise_fma(av[j+3], tm[j+3], a3);
  }
  v2f s = (a0 + a1) + (a2 + a3);
  return s.x + s.y;
}

__global__ __launch_bounds__(512, 2)
void soft_viterbi_kernel(const float* __restrict__ trans,
                         const float* __restrict__ emis,
                         const float* __restrict__ prior,
                         float* __restrict__ out) {
  const int tid  = threadIdx.x;
  const int GR   = tid >> 8;             // group: which batch element
  const int t8   = tid & 255;            // tid within group
  const int w    = t8 >> 6;              // wave within group (0..3)
  const int lane = tid & 63;
  const int k    = lane & 3;             // k-chunk within quad
  const int pid  = lane >> 2;            // state-pair id within wave (0..15)
  const int n0   = 32 * w + 2 * pid;     // first owned state (2 per lane)
  const int b    = 2 * blockIdx.x + GR;  // batch element

  __shared__ __align__(16) float ubuf[2][2][NN];  // [group][pingpong] exchange
  __shared__ __align__(16) float sarr[2][TT];     // [group] 1/alpha~_t[0]
  __shared__ __align__(16) float red[NN];         // transition row sums (shared)
  __shared__ float rsc[2][4];                     // [group] reduction scratch

  const float* emB = emis + (size_t)b * TT * NN;  // uniform batch base
  float* outb      = out  + (size_t)b * TT * NN;  // uniform batch base

  // ---- issue early global loads (prior, em[0..5]) ----
  float2 pr2 = *(const float2*)(prior + n0);
  float2 em0 = *(const float2*)(emB + n0);
  float2 e1  = *(const float2*)(emB + 1 * NN + n0);
  float2 e2  = *(const float2*)(emB + 2 * NN + n0);
  float2 e3  = *(const float2*)(emB + 3 * NN + n0);
  float2 e4  = *(const float2*)(emB + 4 * NN + n0);
  float2 e5  = *(const float2*)(emB + 5 * NN + n0);
  pr2.x = fmaxf(pr2.x, EPSC); pr2.y = fmaxf(pr2.y, EPSC);

  // ---- row sums of clipped transition (threads 0..127 only; shared) ----
  if (tid < NN) {
    const float4* row = (const float4*)(trans + tid * NN);
    float s = 0.f;
    #pragma unroll 8
    for (int j = 0; j < NN / 4; ++j) {
      float4 v = row[j];
      s += fmaxf(v.x, EPSC) + fmaxf(v.y, EPSC) + fmaxf(v.z, EPSC) + fmaxf(v.w, EPSC);
    }
    red[tid] = s;
  }
  __syncthreads();

  // ---- forward fragment (pk-packed): tf2[s][2i+(c>>1)][c&1] = Tn[p][n0+s], p=4(k+4i)+c ----
  v2f tf2[2][16];
  #pragma unroll
  for (int i = 0; i < 8; ++i) {
    #pragma unroll
    for (int c = 0; c < 4; ++c) {
      const int p = 4 * (k + 4 * i) + c;
      const float2 tv = *(const float2*)(trans + p * NN + n0);
      const float rp = red[p];
      tf2[0][2*i + (c >> 1)][c & 1] = fmaxf(tv.x, EPSC) / rp;
      tf2[1][2*i + (c >> 1)][c & 1] = fmaxf(tv.y, EPSC) / rp;
    }
  }
  // ---- backward fragment: tb2[s][...] = Tn[n0+s][4(k+4i)+c] ----
  v2f tb2[2][16];
  #pragma unroll
  for (int s = 0; s < 2; ++s) {
    const float inv = 1.0f / red[n0 + s];
    const float4* rr = (const float4*)(trans + (n0 + s) * NN);
    #pragma unroll
    for (int i = 0; i < 8; ++i) {
      const float4 tv = rr[k + 4 * i];
      tb2[s][2*i+0][0] = fmaxf(tv.x, EPSC) * inv;
      tb2[s][2*i+0][1] = fmaxf(tv.y, EPSC) * inv;
      tb2[s][2*i+1][0] = fmaxf(tv.z, EPSC) * inv;
      tb2[s][2*i+1][1] = fmaxf(tv.w, EPSC) * inv;
    }
  }

  // ---- prior normalization (per group; prior is shared so psum identical) ----
  float vv = (k == 0) ? (pr2.x + pr2.y) : 0.f;
  #pragma unroll
  for (int m = 1; m < 64; m <<= 1) vv += __shfl_xor(vv, m, 64);
  if (lane == 0) rsc[GR][w] = vv;
  __syncthreads();
  const float psum = (rsc[GR][0] + rsc[GR][1]) + (rsc[GR][2] + rsc[GR][3]);

  // ---- u0 = alpha~_0 ----
  float an0 = (pr2.x / psum) * __expf(em0.x);
  float an1 = (pr2.y / psum) * __expf(em0.y);
  if (k == 0) {
    float2 a2v = make_float2(an0, an1);
    *(float2*)&ubuf[GR][0][n0] = a2v;
    *(float2*)(outb + n0) = a2v;
  }
  float dc0 = __expf(e1.x), dc1 = __expf(e1.y);  // d_1
  // Emission ring: slot m&3 holds em[m]; entering step t slots hold em[t+1..t+4].
  float2 rg0 = e4, rg1 = e5, rg2 = e2, rg3 = e3;
  BAR();                           // publish ubuf[*][0]

  // ================= forward =================
  // Invariant entering step t: dc = d_t; slot (t+1)&3 holds em[t+1].
  auto fstep = [&](const float* rb, float* wb, int t, float2& slot) {
    const float r0 = rb[0];                       // broadcast read, lands early
    const float4* rb4 = (const float4*)rb;
    float4 a4[8];
    #pragma unroll
    for (int i = 0; i < 8; ++i) a4[i] = rb4[k + 4 * i];
    const v2f* av = (const v2f*)a4;               // alias, no repack movs
    float z0 = dotpk16(av, tf2[0]);
    float z1 = dotpk16(av, tf2[1]);
    z0 += qswap1(z0); z0 += qswap2(z0);
    z1 += qswap1(z1); z1 += qswap2(z1);
    const float rinv = rcp_fast(r0);              // 1 instr; consistent scale
    an0 = (dc0 * rinv) * z0;
    an1 = (dc1 * rinv) * z1;
    dc0 = __expf(slot.x); dc1 = __expf(slot.y);   // d_{t+1}, off-chain
    const int tpre = (t + 5 < TT) ? (t + 5) : (TT - 1);
    const float* erow = emB + (size_t)tpre * NN;  // uniform row base (SALU)
    slot = *(const float2*)(erow + n0);           // em[t+5], slack 4 steps
    if (k == 0) {
      float2 a2v = make_float2(an0, an1);
      *(float2*)(wb + n0) = a2v;
      if (t < TT - 1) {
        float* orow = outb + (size_t)t * NN;      // uniform row base (SALU)
        *(float2*)(orow + n0) = a2v;              // stash
      }
    }
    if (t8 == 0) sarr[GR][t - 1] = rinv;          // r_{t-1}
    BAR();
  };

  fstep(ubuf[GR][0], ubuf[GR][1], 1, rg2);        // peel t=1,2,3
  fstep(ubuf[GR][1], ubuf[GR][0], 2, rg3);
  fstep(ubuf[GR][0], ubuf[GR][1], 3, rg0);
  for (int t = 4; t < TT; t += 4) {
    fstep(ubuf[GR][1], ubuf[GR][0], t + 0, rg1);
    fstep(ubuf[GR][0], ubuf[GR][1], t + 1, rg2);
    fstep(ubuf[GR][1], ubuf[GR][0], t + 2, rg3);
    fstep(ubuf[GR][0], ubuf[GR][1], t + 3, rg0);
  }
  const float dl0 = dc0, dl1 = dc1;               // = d_{T-1} (clamped ring)

  // ================= final softmax =================
  float v2 = (k == 0) ? (an0 + an1) : 0.f;
  #pragma unroll
  for (int m = 1; m < 64; m <<= 1) v2 += __shfl_xor(v2, m, 64);
  if (lane == 0) rsc[GR][w] = v2;
  __syncthreads();
  const float total = (rsc[GR][0] + rsc[GR][1]) + (rsc[GR][2] + rsc[GR][3]);
  const float itot = 1.0f / total;
  float pc0 = an0 * itot, pc1 = an1 * itot;
  if (k == 0) *(float2*)(outb + (size_t)(TT - 1) * NN + n0) = make_float2(pc0, pc1);

  // One-time drain: forward alpha-stash stores must be visible before the
  // backward pass re-reads them (same-wave vmem ops are not address-ordered).
  asm volatile("s_waitcnt vmcnt(0)" ::: "memory");

  // ---- backward rings: slot m&3 holds em[m] / alpha~[m] ----
  float2 eb2 = *(const float2*)(emB  + (size_t)510 * NN + n0);  // em[510] -> slot 2
  float2 eb1 = *(const float2*)(emB  + (size_t)509 * NN + n0);
  float2 eb0 = *(const float2*)(emB  + (size_t)508 * NN + n0);
  float2 eb3 = *(const float2*)(emB  + (size_t)507 * NN + n0);
  float2 ac2 = *(const float2*)(outb + (size_t)510 * NN + n0);  // alpha~[510]
  float2 ac1 = *(const float2*)(outb + (size_t)509 * NN + n0);
  float2 ac0 = *(const float2*)(outb + (size_t)508 * NN + n0);
  float2 ac3 = *(const float2*)(outb + (size_t)507 * NN + n0);
  const float sl = sarr[GR][TT - 2];
  float g0 = dl0 * sl * rcp_fast(fmaxf(an0, TINY));  // g_{T-2}
  float g1 = dl1 * sl * rcp_fast(fmaxf(an1, TINY));

  // ================= backward =================
  // Invariant entering step t: pc = p_{t+1}, g = g_t, em-slot t&3 = em[t],
  // ec-slot t&3 = alpha~_t.
  auto bstep = [&](float* xb, int t, float2& em_s, float2& ec_s) {
    if (k == 0) *(float2*)(xb + n0) = make_float2(pc0 * g0, pc1 * g1);
    const float sr = sarr[GR][(t > 0) ? (t - 1) : 0];
    const float at0 = ec_s.x, at1 = ec_s.y;       // alpha~_t
    const float gn0 = __expf(em_s.x) * sr * rcp_fast(fmaxf(at0, TINY));  // g_{t-1}
    const float gn1 = __expf(em_s.y) * sr * rcp_fast(fmaxf(at1, TINY));
    const int tp4 = (t >= 4) ? (t - 4) : 0;
    const float* erow = emB  + (size_t)tp4 * NN;  // uniform row bases (SALU)
    const float* arow = outb + (size_t)tp4 * NN;
    em_s = *(const float2*)(erow + n0);           // em[t-4]
    ec_s = *(const float2*)(arow + n0);           // alpha~[t-4]
    BAR();
    const float4* qb4 = (const float4*)xb;
    float4 a4[8];
    #pragma unroll
    for (int i = 0; i < 8; ++i) a4[i] = qb4[k + 4 * i];
    const v2f* av = (const v2f*)a4;               // alias, no repack movs
    float z0 = dotpk16(av, tb2[0]);
    float z1 = dotpk16(av, tb2[1]);
    z0 += qswap1(z0); z0 += qswap2(z0);
    z1 += qswap1(z1); z1 += qswap2(z1);
    pc0 = at0 * z0;                               // p_t
    pc1 = at1 * z1;
    if (k == 0) {
      float* orow = outb + (size_t)t * NN;        // uniform row base (SALU)
      *(float2*)(orow + n0) = make_float2(pc0, pc1);
    }
    g0 = gn0; g1 = gn1;
  };

  bstep(ubuf[GR][0], 510, eb2, ac2);              // peel t=510,509,508
  bstep(ubuf[GR][1], 509, eb1, ac1);
  bstep(ubuf[GR][0], 508, eb0, ac0);
  for (int t = 507; t >= 3; t -= 4) {
    bstep(ubuf[GR][1], t - 0, eb3, ac3);
    bstep(ubuf[GR][0], t - 1, eb2, ac2);
    bstep(ubuf[GR][1], t - 2, eb1, ac1);
    bstep(ubuf[GR][0], t - 3, eb0, ac0);
  }
}

extern "C" void kernel_launch(void* const* d_in, const int* in_sizes, int n_in,
                              void* d_out, int out_size, void* d_ws, size_t ws_size,
                              hipStream_t stream) {
  (void)in_sizes; (void)n_in; (void)d_ws; (void)ws_size; (void)out_size;
  const float* trans = (const float*)d_in[0];
  const float* emis  = (const float*)d_in[1];
  const float* prior = (const float*)d_in[2];
  float* out = (float*)d_out;
  soft_viterbi_kernel<<<dim3(BB / 2), dim3(512), 0, stream>>>(trans, emis, prior, out);
}